// Round 1
// baseline (191.786 us; speedup 1.0000x reference)
//
#include <hip/hip_runtime.h>

#define EPS 1e-5f

__device__ __forceinline__ float tanh_fast(float x) {
    // tanh(x) = 1 - 2/(e^{2x}+1); stable at both ends (no inf/inf)
    float e = __expf(2.0f * x);
    return 1.0f - 2.0f / (e + 1.0f);
}

__device__ __forceinline__ float bn_act(float a, float b, float mu, float v,
                                        float g, float be) {
    return tanh_fast((a + b - mu) * rsqrtf(v + EPS) * g + be);
}

// Block = 128 threads = 2 waves. Each wave owns 16 rows.
// lane = r + 16*q : r = row-in-tile (0..15), q = output-quarter (0..3).
__global__ __launch_bounds__(128, 2) void ontology_fused(
    const float* __restrict__ x,
    const float* __restrict__ Wl, const float* __restrict__ bl,
    const float* __restrict__ gl, const float* __restrict__ betal,
    const float* __restrict__ ml, const float* __restrict__ vl,
    const float* __restrict__ Wm, const float* __restrict__ bm,
    const float* __restrict__ gm, const float* __restrict__ betam,
    const float* __restrict__ mm, const float* __restrict__ vm,
    const float* __restrict__ Wr, const float* __restrict__ br,
    const float* __restrict__ gr, const float* __restrict__ betar,
    const float* __restrict__ mr, const float* __restrict__ vr,
    const float* __restrict__ Wh, const float* __restrict__ bh,
    float* __restrict__ out)
{
    // odd strides (129/257/65) => LDS bank = (r + col) mod 32, conflict-free
    __shared__ float hl_s[2][16][129];   // per-wave: 8 leaves' outputs (128) per row
    __shared__ float hm_s[2][16][257];   // per-wave: all mid outputs (256) per row
    __shared__ float hr_s[2][16][65];    // per-wave: root outputs (64) per row

    const int wid  = threadIdx.x >> 6;
    const int lane = threadIdx.x & 63;
    const int r    = lane & 15;
    const int q    = lane >> 4;
    const int rowbase = blockIdx.x * 32 + wid * 16;
    const int row  = rowbase + r;
    const float* xrow = x + (size_t)row * 1168;

    for (int m = 0; m < 8; ++m) {
        // ---------------- 8 leaves of mid m ----------------
        #pragma unroll
        for (int j = 0; j < 8; ++j) {
            const int l = m * 8 + j;
            const float4* xp = (const float4*)(xrow + l * 16);
            float4 xa = xp[0], xb = xp[1], xc = xp[2], xd = xp[3];
            float xi[16] = {xa.x, xa.y, xa.z, xa.w, xb.x, xb.y, xb.z, xb.w,
                            xc.x, xc.y, xc.z, xc.w, xd.x, xd.y, xd.z, xd.w};
            float a0 = 0.f, a1 = 0.f, a2 = 0.f, a3 = 0.f;
            const float* wp = Wl + (size_t)l * 256 + q * 4;
            #pragma unroll
            for (int i = 0; i < 16; ++i) {
                float4 w = *(const float4*)(wp + i * 16);
                a0 = fmaf(xi[i], w.x, a0);
                a1 = fmaf(xi[i], w.y, a1);
                a2 = fmaf(xi[i], w.z, a2);
                a3 = fmaf(xi[i], w.w, a3);
            }
            const int po = l * 16 + q * 4;
            float4 bb = *(const float4*)(bl + po);
            float4 mu = *(const float4*)(ml + po);
            float4 vv = *(const float4*)(vl + po);
            float4 gg = *(const float4*)(gl + po);
            float4 be = *(const float4*)(betal + po);
            const int c = j * 16 + q * 4;
            hl_s[wid][r][c + 0] = bn_act(a0, bb.x, mu.x, vv.x, gg.x, be.x);
            hl_s[wid][r][c + 1] = bn_act(a1, bb.y, mu.y, vv.y, gg.y, be.y);
            hl_s[wid][r][c + 2] = bn_act(a2, bb.z, mu.z, vv.z, gg.z, be.z);
            hl_s[wid][r][c + 3] = bn_act(a3, bb.w, mu.w, vv.w, gg.w, be.w);
        }
        __syncthreads();   // hl writes visible

        // ---------------- mid m (144 -> 32, this lane: 8 outputs) ----------------
        {
            const float4* xmp = (const float4*)(xrow + 1024 + m * 16);
            float4 xa = xmp[0], xb = xmp[1], xc = xmp[2], xd = xmp[3];
            float xm[16] = {xa.x, xa.y, xa.z, xa.w, xb.x, xb.y, xb.z, xb.w,
                            xc.x, xc.y, xc.z, xc.w, xd.x, xd.y, xd.z, xd.w};
            float acc[8] = {0.f, 0.f, 0.f, 0.f, 0.f, 0.f, 0.f, 0.f};
            const float* wp = Wm + (size_t)m * 144 * 32 + q * 8;
            #pragma unroll
            for (int i = 0; i < 16; ++i) {
                float4 w0 = *(const float4*)(wp + i * 32);
                float4 w1 = *(const float4*)(wp + i * 32 + 4);
                float xi = xm[i];
                acc[0] = fmaf(xi, w0.x, acc[0]); acc[1] = fmaf(xi, w0.y, acc[1]);
                acc[2] = fmaf(xi, w0.z, acc[2]); acc[3] = fmaf(xi, w0.w, acc[3]);
                acc[4] = fmaf(xi, w1.x, acc[4]); acc[5] = fmaf(xi, w1.y, acc[5]);
                acc[6] = fmaf(xi, w1.z, acc[6]); acc[7] = fmaf(xi, w1.w, acc[7]);
            }
            #pragma unroll 8
            for (int i = 0; i < 128; ++i) {
                float xi = hl_s[wid][r][i];
                const float* wq = wp + (size_t)(16 + i) * 32;
                float4 w0 = *(const float4*)(wq);
                float4 w1 = *(const float4*)(wq + 4);
                acc[0] = fmaf(xi, w0.x, acc[0]); acc[1] = fmaf(xi, w0.y, acc[1]);
                acc[2] = fmaf(xi, w0.z, acc[2]); acc[3] = fmaf(xi, w0.w, acc[3]);
                acc[4] = fmaf(xi, w1.x, acc[4]); acc[5] = fmaf(xi, w1.y, acc[5]);
                acc[6] = fmaf(xi, w1.z, acc[6]); acc[7] = fmaf(xi, w1.w, acc[7]);
            }
            const int po = m * 32 + q * 8;
            float4 b0 = *(const float4*)(bm + po),    b1 = *(const float4*)(bm + po + 4);
            float4 u0 = *(const float4*)(mm + po),    u1 = *(const float4*)(mm + po + 4);
            float4 v0 = *(const float4*)(vm + po),    v1 = *(const float4*)(vm + po + 4);
            float4 g0 = *(const float4*)(gm + po),    g1 = *(const float4*)(gm + po + 4);
            float4 e0 = *(const float4*)(betam + po), e1 = *(const float4*)(betam + po + 4);
            const int c = m * 32 + q * 8;
            hm_s[wid][r][c + 0] = bn_act(acc[0], b0.x, u0.x, v0.x, g0.x, e0.x);
            hm_s[wid][r][c + 1] = bn_act(acc[1], b0.y, u0.y, v0.y, g0.y, e0.y);
            hm_s[wid][r][c + 2] = bn_act(acc[2], b0.z, u0.z, v0.z, g0.z, e0.z);
            hm_s[wid][r][c + 3] = bn_act(acc[3], b0.w, u0.w, v0.w, g0.w, e0.w);
            hm_s[wid][r][c + 4] = bn_act(acc[4], b1.x, u1.x, v1.x, g1.x, e1.x);
            hm_s[wid][r][c + 5] = bn_act(acc[5], b1.y, u1.y, v1.y, g1.y, e1.y);
            hm_s[wid][r][c + 6] = bn_act(acc[6], b1.z, u1.z, v1.z, g1.z, e1.z);
            hm_s[wid][r][c + 7] = bn_act(acc[7], b1.w, u1.w, v1.w, g1.w, e1.w);
        }
        __syncthreads();   // hl reads done (safe to overwrite); at m=7 hm visible
    }

    // ---------------- root (272 -> 64, this lane: 16 outputs) ----------------
    {
        const float4* xrp = (const float4*)(xrow + 1152);
        float4 xa = xrp[0], xb = xrp[1], xc = xrp[2], xd = xrp[3];
        float xr[16] = {xa.x, xa.y, xa.z, xa.w, xb.x, xb.y, xb.z, xb.w,
                        xc.x, xc.y, xc.z, xc.w, xd.x, xd.y, xd.z, xd.w};
        float acc[16];
        #pragma unroll
        for (int k = 0; k < 16; ++k) acc[k] = 0.f;
        const float* wp = Wr + q * 16;
        #pragma unroll
        for (int i = 0; i < 16; ++i) {
            float xi = xr[i];
            const float* wq = wp + (size_t)i * 64;
            float4 w0 = *(const float4*)(wq);
            float4 w1 = *(const float4*)(wq + 4);
            float4 w2 = *(const float4*)(wq + 8);
            float4 w3 = *(const float4*)(wq + 12);
            acc[0]  = fmaf(xi, w0.x, acc[0]);  acc[1]  = fmaf(xi, w0.y, acc[1]);
            acc[2]  = fmaf(xi, w0.z, acc[2]);  acc[3]  = fmaf(xi, w0.w, acc[3]);
            acc[4]  = fmaf(xi, w1.x, acc[4]);  acc[5]  = fmaf(xi, w1.y, acc[5]);
            acc[6]  = fmaf(xi, w1.z, acc[6]);  acc[7]  = fmaf(xi, w1.w, acc[7]);
            acc[8]  = fmaf(xi, w2.x, acc[8]);  acc[9]  = fmaf(xi, w2.y, acc[9]);
            acc[10] = fmaf(xi, w2.z, acc[10]); acc[11] = fmaf(xi, w2.w, acc[11]);
            acc[12] = fmaf(xi, w3.x, acc[12]); acc[13] = fmaf(xi, w3.y, acc[13]);
            acc[14] = fmaf(xi, w3.z, acc[14]); acc[15] = fmaf(xi, w3.w, acc[15]);
        }
        #pragma unroll 8
        for (int i = 0; i < 256; ++i) {
            float xi = hm_s[wid][r][i];
            const float* wq = wp + (size_t)(16 + i) * 64;
            float4 w0 = *(const float4*)(wq);
            float4 w1 = *(const float4*)(wq + 4);
            float4 w2 = *(const float4*)(wq + 8);
            float4 w3 = *(const float4*)(wq + 12);
            acc[0]  = fmaf(xi, w0.x, acc[0]);  acc[1]  = fmaf(xi, w0.y, acc[1]);
            acc[2]  = fmaf(xi, w0.z, acc[2]);  acc[3]  = fmaf(xi, w0.w, acc[3]);
            acc[4]  = fmaf(xi, w1.x, acc[4]);  acc[5]  = fmaf(xi, w1.y, acc[5]);
            acc[6]  = fmaf(xi, w1.z, acc[6]);  acc[7]  = fmaf(xi, w1.w, acc[7]);
            acc[8]  = fmaf(xi, w2.x, acc[8]);  acc[9]  = fmaf(xi, w2.y, acc[9]);
            acc[10] = fmaf(xi, w2.z, acc[10]); acc[11] = fmaf(xi, w2.w, acc[11]);
            acc[12] = fmaf(xi, w3.x, acc[12]); acc[13] = fmaf(xi, w3.y, acc[13]);
            acc[14] = fmaf(xi, w3.z, acc[14]); acc[15] = fmaf(xi, w3.w, acc[15]);
        }
        const int po = q * 16;
        #pragma unroll
        for (int k = 0; k < 16; ++k) {
            hr_s[wid][r][po + k] = bn_act(acc[k], br[po + k], mr[po + k],
                                          vr[po + k], gr[po + k], betar[po + k]);
        }
    }
    __syncthreads();   // hr visible

    // ---------------- head (64 -> 10), 160 outputs per wave ----------------
    for (int idx = lane; idx < 160; idx += 64) {
        const int r2 = idx / 10;
        const int t  = idx - r2 * 10;
        float acc = bh[t];
        #pragma unroll 8
        for (int k = 0; k < 64; ++k)
            acc = fmaf(hr_s[wid][r2][k], Wh[k * 10 + t], acc);
        out[(size_t)rowbase * 10 + idx] = acc;
    }
}

extern "C" void kernel_launch(void* const* d_in, const int* in_sizes, int n_in,
                              void* d_out, int out_size, void* d_ws, size_t ws_size,
                              hipStream_t stream) {
    const float* x     = (const float*)d_in[0];
    const float* Wl    = (const float*)d_in[1];
    const float* bl    = (const float*)d_in[2];
    const float* gl    = (const float*)d_in[3];
    const float* betal = (const float*)d_in[4];
    const float* ml    = (const float*)d_in[5];
    const float* vl    = (const float*)d_in[6];
    const float* Wm    = (const float*)d_in[7];
    const float* bm    = (const float*)d_in[8];
    const float* gm    = (const float*)d_in[9];
    const float* betam = (const float*)d_in[10];
    const float* mm    = (const float*)d_in[11];
    const float* vm    = (const float*)d_in[12];
    const float* Wr    = (const float*)d_in[13];
    const float* br    = (const float*)d_in[14];
    const float* gr    = (const float*)d_in[15];
    const float* betar = (const float*)d_in[16];
    const float* mr    = (const float*)d_in[17];
    const float* vr    = (const float*)d_in[18];
    const float* Wh    = (const float*)d_in[19];
    const float* bh    = (const float*)d_in[20];
    float* out = (float*)d_out;

    const int n = in_sizes[0] / 1168;   // 16384
    const int blocks = n / 32;          // 32 rows per block (2 waves x 16 rows)
    ontology_fused<<<blocks, 128, 0, stream>>>(
        x, Wl, bl, gl, betal, ml, vl, Wm, bm, gm, betam, mm, vm,
        Wr, br, gr, betar, mr, vr, Wh, bh, out);
}

// Round 2
// 99.411 us; speedup vs baseline: 1.9292x; 1.9292x over previous
//
#include <hip/hip_runtime.h>

#define EPS 1e-5f

__device__ __forceinline__ float tanh_fast(float x) {
    float e = __expf(2.0f * x);
    return 1.0f - 2.0f / (e + 1.0f);
}

__device__ __forceinline__ float bn_act(float a, float b, float mu, float v,
                                        float g, float be) {
    return tanh_fast((a + b - mu) * rsqrtf(v + EPS) * g + be);
}

// async global->LDS, 16B per lane. dest must be contiguous per wave-instr.
__device__ __forceinline__ void gl_lds16(const float* g, float* l) {
    __builtin_amdgcn_global_load_lds(
        (const __attribute__((address_space(1))) unsigned int*)g,
        (__attribute__((address_space(3))) unsigned int*)l, 16, 0, 0);
}

// Block = 256 threads = 4 waves; each wave owns 4 rows.
// lane = q*4 + r : r = row-in-wave (0..3), q = output-slice (0..15).
// 16 rows/block, grid = 1024 blocks -> 4096 waves = 16 waves/CU target.
__global__ __launch_bounds__(256, 4) void ontology_fused(
    const float* __restrict__ x,
    const float* __restrict__ Wl, const float* __restrict__ bl,
    const float* __restrict__ gl, const float* __restrict__ betal,
    const float* __restrict__ ml, const float* __restrict__ vl,
    const float* __restrict__ Wm, const float* __restrict__ bm,
    const float* __restrict__ gm, const float* __restrict__ betam,
    const float* __restrict__ mm, const float* __restrict__ vm,
    const float* __restrict__ Wr, const float* __restrict__ br,
    const float* __restrict__ gr, const float* __restrict__ betar,
    const float* __restrict__ mr, const float* __restrict__ vr,
    const float* __restrict__ Wh, const float* __restrict__ bh,
    float* __restrict__ out)
{
    // weights staged per-m; hl stride 132 (reads conflict-free: bank=4r+16wid),
    // hm stride 40 (reads conflict-free), Wl_s leaf stride 260 (2-way reads).
    __shared__ __align__(16) float Wm_s[144 * 32];     // 18432 B
    __shared__ __align__(16) float Wl_s[8 * 260];      //  8320 B
    __shared__ __align__(16) float hl_s[16][132];      //  8448 B
    __shared__ __align__(16) float hm_s[16][40];       //  2560 B

    const int tid   = threadIdx.x;
    const int lane  = tid & 63;
    const int r     = lane & 3;
    const int q     = lane >> 2;
    const int row_b = (tid >> 6) * 4 + r;          // 0..15
    const int row   = blockIdx.x * 16 + row_b;
    const float* xrow = x + (size_t)row * 1168;

    auto stage = [&](int m) {
        const float* gm_ = Wm + (size_t)m * 4608;  // 144*32
        #pragma unroll
        for (int i = 0; i < 4; ++i) {
            int c = i * 256 + tid;                 // float4 chunk id
            gl_lds16(gm_ + c * 4, Wm_s + c * 4);
        }
        if (tid < 128) {                            // wave-uniform tail (waves 0,1)
            int c = 1024 + tid;
            gl_lds16(gm_ + c * 4, Wm_s + c * 4);
        }
        const float* gw_ = Wl + (size_t)m * 2048;  // 8 leaves * 256
        #pragma unroll
        for (int i = 0; i < 2; ++i) {
            int c = i * 256 + tid;                 // leaf = c>>6 uniform per wave
            gl_lds16(gw_ + c * 4, Wl_s + (c >> 6) * 260 + (c & 63) * 4);
        }
    };

    // ---------------- root accumulators + xr part (Wr rows 0..15) ------------
    float accR0 = 0.f, accR1 = 0.f, accR2 = 0.f, accR3 = 0.f;
    stage(0);
    {
        const float4* xrp = (const float4*)(xrow + 1152);
        float4 xa = xrp[0], xb = xrp[1], xc = xrp[2], xd = xrp[3];
        float xr[16] = {xa.x, xa.y, xa.z, xa.w, xb.x, xb.y, xb.z, xb.w,
                        xc.x, xc.y, xc.z, xc.w, xd.x, xd.y, xd.z, xd.w};
        const float* wr = Wr + q * 4;
        #pragma unroll
        for (int i = 0; i < 16; ++i) {
            float4 w = *(const float4*)(wr + i * 64);
            accR0 = fmaf(xr[i], w.x, accR0);
            accR1 = fmaf(xr[i], w.y, accR1);
            accR2 = fmaf(xr[i], w.z, accR2);
            accR3 = fmaf(xr[i], w.w, accR3);
        }
    }

    #pragma unroll 1
    for (int m = 0; m < 8; ++m) {
        __syncthreads();   // S_a: staging(m) landed (vmcnt drain before barrier)

        // ---------------- leaf: lane does leaf (q>>1), outputs (q&1)*8..+8 ----
        {
            const int lf = q >> 1;
            const int oh = (q & 1) * 8;
            const float4* xp = (const float4*)(xrow + (m * 8 + lf) * 16);
            float4 xa = xp[0], xb = xp[1], xc = xp[2], xd = xp[3];
            float xi[16] = {xa.x, xa.y, xa.z, xa.w, xb.x, xb.y, xb.z, xb.w,
                            xc.x, xc.y, xc.z, xc.w, xd.x, xd.y, xd.z, xd.w};
            float a0=0.f,a1=0.f,a2=0.f,a3=0.f,a4=0.f,a5=0.f,a6=0.f,a7=0.f;
            const float* wl = Wl_s + lf * 260 + oh;
            #pragma unroll
            for (int i = 0; i < 16; ++i) {
                float4 w0 = *(const float4*)(wl + i * 16);
                float4 w1 = *(const float4*)(wl + i * 16 + 4);
                a0 = fmaf(xi[i], w0.x, a0); a1 = fmaf(xi[i], w0.y, a1);
                a2 = fmaf(xi[i], w0.z, a2); a3 = fmaf(xi[i], w0.w, a3);
                a4 = fmaf(xi[i], w1.x, a4); a5 = fmaf(xi[i], w1.y, a5);
                a6 = fmaf(xi[i], w1.z, a6); a7 = fmaf(xi[i], w1.w, a7);
            }
            const int po = (m * 8 + lf) * 16 + oh;
            float4 b0 = *(const float4*)(bl + po),    b1 = *(const float4*)(bl + po + 4);
            float4 u0 = *(const float4*)(ml + po),    u1 = *(const float4*)(ml + po + 4);
            float4 v0 = *(const float4*)(vl + po),    v1 = *(const float4*)(vl + po + 4);
            float4 g0 = *(const float4*)(gl + po),    g1 = *(const float4*)(gl + po + 4);
            float4 e0 = *(const float4*)(betal + po), e1 = *(const float4*)(betal + po + 4);
            float4 h0, h1;
            h0.x = bn_act(a0, b0.x, u0.x, v0.x, g0.x, e0.x);
            h0.y = bn_act(a1, b0.y, u0.y, v0.y, g0.y, e0.y);
            h0.z = bn_act(a2, b0.z, u0.z, v0.z, g0.z, e0.z);
            h0.w = bn_act(a3, b0.w, u0.w, v0.w, g0.w, e0.w);
            h1.x = bn_act(a4, b1.x, u1.x, v1.x, g1.x, e1.x);
            h1.y = bn_act(a5, b1.y, u1.y, v1.y, g1.y, e1.y);
            h1.z = bn_act(a6, b1.z, u1.z, v1.z, g1.z, e1.z);
            h1.w = bn_act(a7, b1.w, u1.w, v1.w, g1.w, e1.w);
            *(float4*)(&hl_s[row_b][q * 8])     = h0;   // col = 8q .. 8q+7
            *(float4*)(&hl_s[row_b][q * 8 + 4]) = h1;
        }
        __syncthreads();   // S_b: hl visible

        // ---------------- mid: lane computes outputs q*2, q*2+1 --------------
        {
            const float4* xmp = (const float4*)(xrow + 1024 + m * 16);
            float4 xa = xmp[0], xb = xmp[1], xc = xmp[2], xd = xmp[3];
            float xm[16] = {xa.x, xa.y, xa.z, xa.w, xb.x, xb.y, xb.z, xb.w,
                            xc.x, xc.y, xc.z, xc.w, xd.x, xd.y, xd.z, xd.w};
            float s0 = 0.f, s1 = 0.f;
            const float* wm = Wm_s + q * 2;
            #pragma unroll
            for (int i = 0; i < 16; ++i) {
                float2 w = *(const float2*)(wm + i * 32);
                s0 = fmaf(xm[i], w.x, s0);
                s1 = fmaf(xm[i], w.y, s1);
            }
            #pragma unroll 8
            for (int i4 = 0; i4 < 32; ++i4) {
                float4 h = *(const float4*)(&hl_s[row_b][i4 * 4]);
                const float* wq = wm + (16 + i4 * 4) * 32;
                float2 w0 = *(const float2*)(wq);
                float2 w1 = *(const float2*)(wq + 32);
                float2 w2 = *(const float2*)(wq + 64);
                float2 w3 = *(const float2*)(wq + 96);
                s0 = fmaf(h.x, w0.x, s0); s1 = fmaf(h.x, w0.y, s1);
                s0 = fmaf(h.y, w1.x, s0); s1 = fmaf(h.y, w1.y, s1);
                s0 = fmaf(h.z, w2.x, s0); s1 = fmaf(h.z, w2.y, s1);
                s0 = fmaf(h.w, w3.x, s0); s1 = fmaf(h.w, w3.y, s1);
            }
            const int po = m * 32 + q * 2;
            float2 bb = *(const float2*)(bm + po);
            float2 uu = *(const float2*)(mm + po);
            float2 vv = *(const float2*)(vm + po);
            float2 gg = *(const float2*)(gm + po);
            float2 ee = *(const float2*)(betam + po);
            float2 h2;
            h2.x = bn_act(s0, bb.x, uu.x, vv.x, gg.x, ee.x);
            h2.y = bn_act(s1, bb.y, uu.y, vv.y, gg.y, ee.y);
            *(float2*)(&hm_s[row_b][q * 2]) = h2;
        }
        __syncthreads();   // S_c: hm visible; Wl_s/Wm_s free to overwrite

        if (m < 7) stage(m + 1);   // overlap staging with root accumulation

        // ---------------- root accumulate: Wr rows 16+m*32 .. +32 -------------
        {
            const float* wr = Wr + (size_t)(16 + m * 32) * 64 + q * 4;
            #pragma unroll
            for (int i4 = 0; i4 < 8; ++i4) {
                float4 h = *(const float4*)(&hm_s[row_b][i4 * 4]);
                float4 w0 = *(const float4*)(wr + (i4 * 4 + 0) * 64);
                float4 w1 = *(const float4*)(wr + (i4 * 4 + 1) * 64);
                float4 w2 = *(const float4*)(wr + (i4 * 4 + 2) * 64);
                float4 w3 = *(const float4*)(wr + (i4 * 4 + 3) * 64);
                accR0 = fmaf(h.x, w0.x, accR0); accR1 = fmaf(h.x, w0.y, accR1);
                accR2 = fmaf(h.x, w0.z, accR2); accR3 = fmaf(h.x, w0.w, accR3);
                accR0 = fmaf(h.y, w1.x, accR0); accR1 = fmaf(h.y, w1.y, accR1);
                accR2 = fmaf(h.y, w1.z, accR2); accR3 = fmaf(h.y, w1.w, accR3);
                accR0 = fmaf(h.z, w2.x, accR0); accR1 = fmaf(h.z, w2.y, accR1);
                accR2 = fmaf(h.z, w2.z, accR2); accR3 = fmaf(h.z, w2.w, accR3);
                accR0 = fmaf(h.w, w3.x, accR0); accR1 = fmaf(h.w, w3.y, accR1);
                accR2 = fmaf(h.w, w3.z, accR2); accR3 = fmaf(h.w, w3.w, accR3);
            }
        }
    }

    // ---------------- root BN+tanh (4 outs/lane, in regs) --------------------
    const int po = q * 4;
    float4 rb = *(const float4*)(br + po);
    float4 ru = *(const float4*)(mr + po);
    float4 rv = *(const float4*)(vr + po);
    float4 rg = *(const float4*)(gr + po);
    float4 re = *(const float4*)(betar + po);
    float hr[4];
    hr[0] = bn_act(accR0, rb.x, ru.x, rv.x, rg.x, re.x);
    hr[1] = bn_act(accR1, rb.y, ru.y, rv.y, rg.y, re.y);
    hr[2] = bn_act(accR2, rb.z, ru.z, rv.z, rg.z, re.z);
    hr[3] = bn_act(accR3, rb.w, ru.w, rv.w, rg.w, re.w);

    // ---------------- head: partials + butterfly over the 16 q-lanes ---------
    float p[10] = {0.f,0.f,0.f,0.f,0.f,0.f,0.f,0.f,0.f,0.f};
    #pragma unroll
    for (int j = 0; j < 4; ++j) {
        const float* wh = Wh + (q * 4 + j) * 10;
        #pragma unroll
        for (int t2 = 0; t2 < 5; ++t2) {
            float2 w = *(const float2*)(wh + t2 * 2);
            p[t2 * 2]     = fmaf(hr[j], w.x, p[t2 * 2]);
            p[t2 * 2 + 1] = fmaf(hr[j], w.y, p[t2 * 2 + 1]);
        }
    }
    #pragma unroll
    for (int t = 0; t < 10; ++t) {
        p[t] += __shfl_xor(p[t], 4, 64);
        p[t] += __shfl_xor(p[t], 8, 64);
        p[t] += __shfl_xor(p[t], 16, 64);
        p[t] += __shfl_xor(p[t], 32, 64);
    }
    if (q == 0) {
        float* op = out + (size_t)row * 10;
        #pragma unroll
        for (int t = 0; t < 10; ++t) op[t] = p[t] + bh[t];
    }
}

extern "C" void kernel_launch(void* const* d_in, const int* in_sizes, int n_in,
                              void* d_out, int out_size, void* d_ws, size_t ws_size,
                              hipStream_t stream) {
    const float* x     = (const float*)d_in[0];
    const float* Wl    = (const float*)d_in[1];
    const float* bl    = (const float*)d_in[2];
    const float* gl    = (const float*)d_in[3];
    const float* betal = (const float*)d_in[4];
    const float* ml    = (const float*)d_in[5];
    const float* vl    = (const float*)d_in[6];
    const float* Wm    = (const float*)d_in[7];
    const float* bm    = (const float*)d_in[8];
    const float* gm    = (const float*)d_in[9];
    const float* betam = (const float*)d_in[10];
    const float* mm    = (const float*)d_in[11];
    const float* vm    = (const float*)d_in[12];
    const float* Wr    = (const float*)d_in[13];
    const float* br    = (const float*)d_in[14];
    const float* gr    = (const float*)d_in[15];
    const float* betar = (const float*)d_in[16];
    const float* mr    = (const float*)d_in[17];
    const float* vr    = (const float*)d_in[18];
    const float* Wh    = (const float*)d_in[19];
    const float* bh    = (const float*)d_in[20];
    float* out = (float*)d_out;

    const int n = in_sizes[0] / 1168;   // 16384
    const int blocks = n / 16;          // 16 rows per block (4 waves x 4 rows)
    ontology_fused<<<blocks, 256, 0, stream>>>(
        x, Wl, bl, gl, betal, ml, vl, Wm, bm, gm, betam, mm, vm,
        Wr, br, gr, betar, mr, vr, Wh, bh, out);
}

// Round 3
// 35.552 us; speedup vs baseline: 5.3945x; 2.7962x over previous
//
#include <hip/hip_runtime.h>

typedef __attribute__((ext_vector_type(8))) short bf16x8;
typedef __attribute__((ext_vector_type(4))) float f32x4;

#define EPS 1e-5f

// ws layout: frag blocks (182 x 1KB bf16) then fp32 ST region
#define N_FRAG_BLOCKS 182
#define WSB_LEAF 0      // 64 blocks: leaf l
#define WSB_MID  64     // 80 blocks: (m*2+t)*5 + s
#define WSB_ROOT 144    // 36 blocks: t*9 + s
#define WSB_HEAD 180    // 2 blocks: s
#define ST_SL 0
#define ST_TL 1024
#define ST_SM 2048
#define ST_TM 2304
#define ST_SR 2560
#define ST_TR 2624
#define WS_ST_BYTE_OFF (N_FRAG_BLOCKS * 1024)

__device__ __forceinline__ unsigned short f2bf(float f) {  // RNE float->bf16
    unsigned u = __float_as_uint(f);
    unsigned r = u + 0x7fffu + ((u >> 16) & 1u);
    return (unsigned short)(r >> 16);
}

__device__ __forceinline__ unsigned pack2bf(float a, float b) {
    return (unsigned)f2bf(a) | ((unsigned)f2bf(b) << 16);
}

__device__ __forceinline__ bf16x8 pack8(float4 a, float4 b) {
    union { unsigned u[4]; bf16x8 v; } r;
    r.u[0] = pack2bf(a.x, a.y); r.u[1] = pack2bf(a.z, a.w);
    r.u[2] = pack2bf(b.x, b.y); r.u[3] = pack2bf(b.z, b.w);
    return r.v;
}

__device__ __forceinline__ float tanh_fast(float x) {
    float e = __expf(2.0f * x);
    return 1.0f - 2.0f / (e + 1.0f);
}

// ---------------- prep: fragment-ordered bf16 weights + folded BN ----------
__global__ void ontology_prep(
    const float* __restrict__ Wl, const float* __restrict__ Wm,
    const float* __restrict__ Wr, const float* __restrict__ Wh,
    const float* __restrict__ bl, const float* __restrict__ gl,
    const float* __restrict__ betal, const float* __restrict__ ml,
    const float* __restrict__ vl,
    const float* __restrict__ bm, const float* __restrict__ gm,
    const float* __restrict__ betam, const float* __restrict__ mm,
    const float* __restrict__ vm,
    const float* __restrict__ br, const float* __restrict__ gr,
    const float* __restrict__ betar, const float* __restrict__ mr,
    const float* __restrict__ vr,
    unsigned short* __restrict__ wsFrag, float* __restrict__ wsST)
{
    const int b = blockIdx.x;
    const int t = threadIdx.x;
    if (b < N_FRAG_BLOCKS) {
        // A'-frag layout (transposed weights): lane t holds A'[row=t&15][k=(t>>4)*8+i]
        const int row = t & 15, g = t >> 4;
        unsigned short vals[8];
        #pragma unroll
        for (int i = 0; i < 8; ++i) {
            const int k = g * 8 + i;
            float v = 0.f;
            if (b < 64) {                       // leaf l: pair-packed K
                const int l = b;
                if ((l & 1) == 0) { if (k < 16)  v = Wl[l * 256 + k * 16 + row]; }
                else              { if (k >= 16) v = Wl[l * 256 + (k - 16) * 16 + row]; }
            } else if (b < 144) {               // mid
                const int idx = b - 64, m = idx / 10, rem = idx % 10;
                const int tt = rem / 5, s = rem % 5;
                const int krow = s * 32 + k;
                if (krow < 144) v = Wm[m * 4608 + krow * 32 + tt * 16 + row];
            } else if (b < 180) {               // root
                const int idx = b - 144, tt = idx / 9, s = idx % 9;
                if (s == 0) { if (k < 16) v = Wr[k * 64 + tt * 16 + row]; }
                else { const int krow = 16 + (s - 1) * 32 + k;
                       v = Wr[krow * 64 + tt * 16 + row]; }
            } else {                            // head
                const int s = b - 180, krow = s * 32 + k;
                if (row < 10) v = Wh[krow * 10 + row];
            }
            vals[i] = f2bf(v);
        }
        #pragma unroll
        for (int i = 0; i < 8; ++i) wsFrag[b * 512 + t * 8 + i] = vals[i];
    } else if (b == N_FRAG_BLOCKS) {            // leaf ST (1024)
        for (int i = 0; i < 16; ++i) {
            const int id = t + 64 * i;
            const float S = gl[id] * rsqrtf(vl[id] + EPS);
            wsST[ST_SL + id] = S;
            wsST[ST_TL + id] = (bl[id] - ml[id]) * S + betal[id];
        }
    } else if (b == N_FRAG_BLOCKS + 1) {        // mid ST (256)
        for (int i = 0; i < 4; ++i) {
            const int id = t + 64 * i;
            const float S = gm[id] * rsqrtf(vm[id] + EPS);
            wsST[ST_SM + id] = S;
            wsST[ST_TM + id] = (bm[id] - mm[id]) * S + betam[id];
        }
    } else {                                     // root ST (64)
        const int id = t;
        const float S = gr[id] * rsqrtf(vr[id] + EPS);
        wsST[ST_SR + id] = S;
        wsST[ST_TR + id] = (br[id] - mr[id]) * S + betar[id];
    }
}

// ---------------- main fused MFMA kernel -----------------------------------
// Block = 256 thr = 4 waves = one 16-row M-tile. Wave w: mids 2w,2w+1 (+16
// leaves), root col-tile w. All outputs computed TRANSPOSED (feat rows x
// sample cols) so lane (c=lane&15 sample, g=lane>>4) holds 4 contiguous
// features -> b64 LDS writes, float4 BN loads. 2 barriers total.
__global__ __launch_bounds__(256, 4) void ontology_mfma(
    const float* __restrict__ x,
    const unsigned short* __restrict__ wsFrag,
    const float* __restrict__ wsST,
    const float* __restrict__ bh,
    float* __restrict__ out)
{
    // strides in bf16: 168 (=21*8), 264 (=33*8), 72 (=9*8): s4 odd => both
    // b128 reads and b64 writes bank-conflict-free (see analysis).
    __shared__ __align__(16) unsigned short mid_in[4][16][168];  // per-wave
    __shared__ __align__(16) unsigned short hm[16][264];         // shared
    unsigned short (*hr)[72] = (unsigned short (*)[72])&mid_in[0][0][0]; // alias, post-barrier-1

    const int w    = threadIdx.x >> 6;
    const int lane = threadIdx.x & 63;
    const int c    = lane & 15;       // sample within tile
    const int g    = lane >> 4;       // k/feat group
    const int rowbase = blockIdx.x * 16;
    const float* xrow = x + (size_t)(rowbase + c) * 1168;

    // zero pad-K columns 144..159 of this wave's mid_in (written once)
    {
        uint2 z = {0u, 0u};
        *(uint2*)&mid_in[w][c][144 + 4 * g] = z;
    }

    const float* Sl = wsST + ST_SL, *Tl = wsST + ST_TL;
    const float* Sm = wsST + ST_SM, *Tm = wsST + ST_TM;
    const float* Sr = wsST + ST_SR, *Tr = wsST + ST_TR;

    #pragma unroll 1
    for (int mi = 0; mi < 2; ++mi) {
        const int mm = w * 2 + mi;
        // stage xm (cols 0..15) into mid_in
        {
            float4 xm4 = *(const float4*)(xrow + 1024 + mm * 16 + 4 * g);
            uint2 p; p.x = pack2bf(xm4.x, xm4.y); p.y = pack2bf(xm4.z, xm4.w);
            *(uint2*)&mid_in[w][c][4 * g] = p;
        }
        // 4 leaf-pairs -> 8 leaves, outputs into mid_in cols 16..143
        #pragma unroll
        for (int p = 0; p < 4; ++p) {
            const int pair = mm * 4 + p;
            const float* xp = xrow + pair * 32 + g * 8;
            float4 xa = *(const float4*)xp;
            float4 xb = *(const float4*)(xp + 4);
            bf16x8 bfrag = pack8(xa, xb);       // shared by both leaves of pair
            #pragma unroll
            for (int e = 0; e < 2; ++e) {
                const int leaf = pair * 2 + e;
                bf16x8 afrag = *(const bf16x8*)(wsFrag + (WSB_LEAF + leaf) * 512 + lane * 8);
                f32x4 acc = {0.f, 0.f, 0.f, 0.f};
                acc = __builtin_amdgcn_mfma_f32_16x16x32_bf16(afrag, bfrag, acc, 0, 0, 0);
                float4 S = *(const float4*)(Sl + leaf * 16 + 4 * g);
                float4 T = *(const float4*)(Tl + leaf * 16 + 4 * g);
                float h0 = tanh_fast(acc[0] * S.x + T.x);
                float h1 = tanh_fast(acc[1] * S.y + T.y);
                float h2 = tanh_fast(acc[2] * S.z + T.z);
                float h3 = tanh_fast(acc[3] * S.w + T.w);
                uint2 pk; pk.x = pack2bf(h0, h1); pk.y = pack2bf(h2, h3);
                *(uint2*)&mid_in[w][c][16 + (p * 2 + e) * 16 + 4 * g] = pk;
            }
        }
        // mid mm: 2 col-tiles x 5 K-steps
        {
            f32x4 acc0 = {0.f, 0.f, 0.f, 0.f};
            f32x4 acc1 = {0.f, 0.f, 0.f, 0.f};
            const unsigned short* fb = wsFrag + (WSB_MID + mm * 10) * 512 + lane * 8;
            #pragma unroll
            for (int s = 0; s < 5; ++s) {
                bf16x8 bfrag = *(const bf16x8*)&mid_in[w][c][s * 32 + g * 8];
                bf16x8 a0 = *(const bf16x8*)(fb + s * 512);
                bf16x8 a1 = *(const bf16x8*)(fb + (5 + s) * 512);
                acc0 = __builtin_amdgcn_mfma_f32_16x16x32_bf16(a0, bfrag, acc0, 0, 0, 0);
                acc1 = __builtin_amdgcn_mfma_f32_16x16x32_bf16(a1, bfrag, acc1, 0, 0, 0);
            }
            #pragma unroll
            for (int t = 0; t < 2; ++t) {
                f32x4 acc = t ? acc1 : acc0;
                const int po = mm * 32 + t * 16 + 4 * g;
                float4 S = *(const float4*)(Sm + po);
                float4 T = *(const float4*)(Tm + po);
                float h0 = tanh_fast(acc[0] * S.x + T.x);
                float h1 = tanh_fast(acc[1] * S.y + T.y);
                float h2 = tanh_fast(acc[2] * S.z + T.z);
                float h3 = tanh_fast(acc[3] * S.w + T.w);
                uint2 pk; pk.x = pack2bf(h0, h1); pk.y = pack2bf(h2, h3);
                *(uint2*)&hm[c][po] = pk;
            }
        }
    }
    __syncthreads();   // barrier 1: hm complete (all waves)

    // root col-tile w: 9 K-steps (s=0 = x part, s=1..8 = hm)
    {
        f32x4 acc = {0.f, 0.f, 0.f, 0.f};
        const unsigned short* fb = wsFrag + (WSB_ROOT + w * 9) * 512 + lane * 8;
        {
            const float* xp = xrow + 1152 + (g & 1) * 8;   // k>=16 rows of A' are 0
            float4 xa = *(const float4*)xp;
            float4 xb = *(const float4*)(xp + 4);
            bf16x8 bfrag = pack8(xa, xb);
            bf16x8 a0 = *(const bf16x8*)fb;
            acc = __builtin_amdgcn_mfma_f32_16x16x32_bf16(a0, bfrag, acc, 0, 0, 0);
        }
        #pragma unroll
        for (int s = 1; s <= 8; ++s) {
            bf16x8 bfrag = *(const bf16x8*)&hm[c][(s - 1) * 32 + g * 8];
            bf16x8 a0 = *(const bf16x8*)(fb + s * 512);
            acc = __builtin_amdgcn_mfma_f32_16x16x32_bf16(a0, bfrag, acc, 0, 0, 0);
        }
        const int po = w * 16 + 4 * g;
        float4 S = *(const float4*)(Sr + po);
        float4 T = *(const float4*)(Tr + po);
        float h0 = tanh_fast(acc[0] * S.x + T.x);
        float h1 = tanh_fast(acc[1] * S.y + T.y);
        float h2 = tanh_fast(acc[2] * S.z + T.z);
        float h3 = tanh_fast(acc[3] * S.w + T.w);
        uint2 pk; pk.x = pack2bf(h0, h1); pk.y = pack2bf(h2, h3);
        *(uint2*)&hr[c][po] = pk;
    }
    __syncthreads();   // barrier 2: hr complete

    // head (wave 0 only): tasks in rows, samples in cols
    if (w == 0) {
        f32x4 acc = {0.f, 0.f, 0.f, 0.f};
        #pragma unroll
        for (int s = 0; s < 2; ++s) {
            bf16x8 bfrag = *(const bf16x8*)&hr[c][s * 32 + g * 8];
            bf16x8 a0 = *(const bf16x8*)(wsFrag + (WSB_HEAD + s) * 512 + lane * 8);
            acc = __builtin_amdgcn_mfma_f32_16x16x32_bf16(a0, bfrag, acc, 0, 0, 0);
        }
        float* op = out + (size_t)(rowbase + c) * 10 + 4 * g;
        if (g < 2) {
            float2 o1 = {acc[0] + bh[4 * g],     acc[1] + bh[4 * g + 1]};
            float2 o2 = {acc[2] + bh[4 * g + 2], acc[3] + bh[4 * g + 3]};
            *(float2*)op = o1;
            *(float2*)(op + 2) = o2;
        } else if (g == 2) {
            float2 o1 = {acc[0] + bh[8], acc[1] + bh[9]};
            *(float2*)op = o1;
        }
    }
}

extern "C" void kernel_launch(void* const* d_in, const int* in_sizes, int n_in,
                              void* d_out, int out_size, void* d_ws, size_t ws_size,
                              hipStream_t stream) {
    const float* x     = (const float*)d_in[0];
    const float* Wl    = (const float*)d_in[1];
    const float* bl    = (const float*)d_in[2];
    const float* gl    = (const float*)d_in[3];
    const float* betal = (const float*)d_in[4];
    const float* ml    = (const float*)d_in[5];
    const float* vl    = (const float*)d_in[6];
    const float* Wm    = (const float*)d_in[7];
    const float* bm    = (const float*)d_in[8];
    const float* gm    = (const float*)d_in[9];
    const float* betam = (const float*)d_in[10];
    const float* mm    = (const float*)d_in[11];
    const float* vm    = (const float*)d_in[12];
    const float* Wr    = (const float*)d_in[13];
    const float* br    = (const float*)d_in[14];
    const float* gr    = (const float*)d_in[15];
    const float* betar = (const float*)d_in[16];
    const float* mr    = (const float*)d_in[17];
    const float* vr    = (const float*)d_in[18];
    const float* Wh    = (const float*)d_in[19];
    const float* bh    = (const float*)d_in[20];
    float* out = (float*)d_out;

    unsigned short* wsFrag = (unsigned short*)d_ws;
    float* wsST = (float*)((char*)d_ws + WS_ST_BYTE_OFF);

    ontology_prep<<<N_FRAG_BLOCKS + 3, 64, 0, stream>>>(
        Wl, Wm, Wr, Wh, bl, gl, betal, ml, vl, bm, gm, betam, mm, vm,
        br, gr, betar, mr, vr, wsFrag, wsST);

    const int n = in_sizes[0] / 1168;   // 16384
    ontology_mfma<<<n / 16, 256, 0, stream>>>(x, wsFrag, wsST, bh, out);
}